// Round 12
// baseline (73.385 us; speedup 1.0000x reference)
//
#include <hip/hip_runtime.h>
#include <hip/hip_bf16.h>
#include <cmath>

// Problem constants (from reference setup_inputs)
#define BB 64
#define LL 512
#define NN 64
#define AA 64
#define PP 16
#define DD 256
#define MAX_OFF 4.0f
#define STRIDE_S 8

typedef __attribute__((ext_vector_type(8))) short short8_t;   // 8 bf16 = 4 VGPR
typedef __attribute__((ext_vector_type(4))) float float4_t;   // MFMA C/D

// fp32 -> bf16 round-to-nearest-even (finite inputs)
static __device__ __forceinline__ unsigned f2bf(float x) {
    union { float f; unsigned u; } v; v.f = x;
    return (v.u + 0x7FFFu + ((v.u >> 16) & 1u)) >> 16;
}

// ---------------------------------------------------------------------------
// Kernel 1a: conv1d(N->32, k=3, zero pad 1) + ReLU + partial sum over l-chunk.
// grid = (8 chunks, B). block = 256 (o = t&31, lgroup = t>>5, 8 l each).
// ---------------------------------------------------------------------------
__global__ __launch_bounds__(256) void conv_pool_kernel(
    const float* __restrict__ x,        // (B, L, N)
    const float* __restrict__ conv_w,   // (32, N, 3)
    const float* __restrict__ conv_b,   // (32)
    float* __restrict__ pool_partial)   // (B, 8, 32)
{
    const int c = blockIdx.x;   // l-chunk (64 wide)
    const int b = blockIdx.y;
    const int t = threadIdx.x;

    __shared__ float4 wl[3 * 16 * 32];   // [k][nv][o] as float4 over n
    __shared__ float  xl[66 * 64];       // rows c*64-1 .. c*64+64, stride 64
    __shared__ float  red[8][32];

    // stage weights transposed: wl[(k*16+nv)*32 + o] = conv_w[o][nv*4+0..3][k]
    for (int idx = t; idx < 1536; idx += 256) {
        int o  = idx & 31;
        int nv = (idx >> 5) & 15;
        int k  = idx >> 9;
        float4 v;
        v.x = conv_w[(o * 64 + nv * 4 + 0) * 3 + k];
        v.y = conv_w[(o * 64 + nv * 4 + 1) * 3 + k];
        v.z = conv_w[(o * 64 + nv * 4 + 2) * 3 + k];
        v.w = conv_w[(o * 64 + nv * 4 + 3) * 3 + k];
        wl[idx] = v;
    }

    // stage x rows (zero padding outside [0, L))
    const int base_row = c * 64 - 1;
    for (int idx = t; idx < 66 * 16; idx += 256) {
        int j  = idx >> 4;
        int nv = idx & 15;
        int row = base_row + j;
        float4 v = make_float4(0.f, 0.f, 0.f, 0.f);
        if (row >= 0 && row < LL)
            v = *reinterpret_cast<const float4*>(&x[((size_t)b * LL + row) * NN + nv * 4]);
        *reinterpret_cast<float4*>(&xl[j * 64 + nv * 4]) = v;
    }
    __syncthreads();

    const int o  = t & 31;
    const int lg = t >> 5;    // 0..7  -> local l = lg*8 .. lg*8+7

    float s[8];
#pragma unroll
    for (int j = 0; j < 8; ++j) s[j] = 0.f;

#pragma unroll
    for (int nv = 0; nv < 16; ++nv) {
        float4 xv[10];
#pragma unroll
        for (int j = 0; j < 10; ++j)
            xv[j] = *reinterpret_cast<const float4*>(&xl[(lg * 8 + j) * 64 + nv * 4]);
#pragma unroll
        for (int k = 0; k < 3; ++k) {
            float4 w4 = wl[(k * 16 + nv) * 32 + o];
#pragma unroll
            for (int j = 0; j < 8; ++j) {
                s[j] = fmaf(xv[j + k].x, w4.x, s[j]);
                s[j] = fmaf(xv[j + k].y, w4.y, s[j]);
                s[j] = fmaf(xv[j + k].z, w4.z, s[j]);
                s[j] = fmaf(xv[j + k].w, w4.w, s[j]);
            }
        }
    }

    const float cb = conv_b[o];
    float part = 0.f;
#pragma unroll
    for (int j = 0; j < 8; ++j) part += fmaxf(s[j] + cb, 0.f);
    red[lg][o] = part;
    __syncthreads();

    if (t < 32) {
        float sum = 0.f;
#pragma unroll
        for (int g = 0; g < 8; ++g) sum += red[g][t];
        pool_partial[((size_t)b * 8 + c) * 32 + t] = sum;
    }
}

// ---------------------------------------------------------------------------
// Kernel 1b: reduce partials -> pooled mean -> linear(32->A) -> 4*tanh.
// Block 0 additionally converts wp_w to bf16 into ws (read by kernel 2).
// grid = B, block = 64 (one thread per a).
// ---------------------------------------------------------------------------
__global__ __launch_bounds__(64) void delta_kernel(
    const float* __restrict__ pool_partial, // (B, 8, 32)
    const float* __restrict__ lin_w,        // (A, 32)
    const float* __restrict__ lin_b,        // (A)
    const float* __restrict__ wp_w,         // (D, P)
    float* __restrict__ delta,              // (B, A)
    unsigned short* __restrict__ wp16)      // (D*P) bf16
{
    const int b = blockIdx.x;
    const int t = threadIdx.x;
    __shared__ float pooled[32];

    if (t < 32) {
        float s = 0.f;
#pragma unroll
        for (int c = 0; c < 8; ++c) s += pool_partial[((size_t)b * 8 + c) * 32 + t];
        pooled[t] = s * (1.0f / 512.0f);
    }
    __syncthreads();

    float s = lin_b[t];
#pragma unroll
    for (int o = 0; o < 32; ++o) s = fmaf(pooled[o], lin_w[t * 32 + o], s);
    delta[b * AA + t] = MAX_OFF * tanhf(s);

    // one block converts wp_w (4096 floats) to bf16
    if (b == 0) {
        const float4* w4 = reinterpret_cast<const float4*>(wp_w);
        uint2* o2 = reinterpret_cast<uint2*>(wp16);
#pragma unroll
        for (int i = 0; i < 16; ++i) {
            float4 v = w4[i * 64 + t];
            uint2 pk;
            pk.x = f2bf(v.x) | (f2bf(v.y) << 16);
            pk.y = f2bf(v.z) | (f2bf(v.w) << 16);
            o2[i * 64 + t] = pk;
        }
    }
}

// ---------------------------------------------------------------------------
// Phase 1: materialize samp to ws as [b][n][a][p] bf16 (8 MB).
// grid = (A, B), block = 64 (one wave, no LDS, no barriers).
// For fixed p, i0/i1 are wave-uniform -> x[b,i0,lane] is a coalesced 256B
// load (validated pattern in R9). Each lane packs its 16 p-values into 8
// dwords and writes them as two uint4 (32B contiguous per lane).
// ---------------------------------------------------------------------------
__global__ __launch_bounds__(64) void samp_kernel(
    const float* __restrict__ x,       // (B, L, N)
    const float* __restrict__ delta,   // (B, A)
    unsigned* __restrict__ samp_dw)    // (B*N*A*8) dwords = [b][n][a][p-pair]
{
    const int a    = blockIdx.x;
    const int b    = blockIdx.y;
    const int lane = threadIdx.x;   // = n

    const float dlt  = delta[b * AA + a];
    const float base = (float)(a * STRIDE_S) - 7.5f + dlt;
    const float* xb  = x + (size_t)b * (LL * NN);

    unsigned pk[8];
#pragma unroll
    for (int pq = 0; pq < 8; ++pq) {
        unsigned v = 0;
#pragma unroll
        for (int q = 0; q < 2; ++q) {
            float xs = base + (float)(pq * 2 + q);
            xs = fminf(fmaxf(xs, 0.f), (float)(LL - 1));
            int   i0 = (int)floorf(xs);
            float f  = xs - (float)i0;
            int   i1 = min(i0 + 1, LL - 1);
            float g0 = xb[i0 * NN + lane];    // coalesced (i0 wave-uniform)
            float g1 = xb[i1 * NN + lane];
            v |= f2bf(g0 + f * (g1 - g0)) << (16 * q);
        }
        pk[pq] = v;
    }
    unsigned* dst = samp_dw + ((size_t)(b * NN + lane) * AA + a) * 8;
    *reinterpret_cast<uint4*>(dst + 0) = make_uint4(pk[0], pk[1], pk[2], pk[3]);
    *reinterpret_cast<uint4*>(dst + 4) = make_uint4(pk[4], pk[5], pk[6], pk[7]);
}

// ---------------------------------------------------------------------------
// Phase 2: PURE STREAMING projection. grid = 4096 (flat plane id), block 256.
// Block `plane` = (b*64+n) reads its contiguous 2KB samp chunk [a=64][p=16]
// + wp16 (L2-hot), runs 16 MFMAs, writes out[plane] = [a=64][d=256] =
// 64 KB CONTIGUOUS, planes in flat order -> device-wide sequential write
// stream (fill-like). No LDS, no barriers.
// MFMA: A = wp (M=d), B = samp (N=a), K=16 padded to 32 (A k>=16 zero).
// C layout row=d -> thread's 4 acc regs = 4 consecutive d -> dwordx4.
// ---------------------------------------------------------------------------
__global__ __launch_bounds__(256) void stream_proj_kernel(
    const unsigned short* __restrict__ wp16,   // (D, P) bf16
    const float* __restrict__ wp_b,            // (D)
    const unsigned* __restrict__ samp_dw,      // [b][n][a][p-pair] dwords
    float* __restrict__ out)                   // (B*N, A, D)
{
    const int plane = blockIdx.x;   // b*64 + n
    const int t = threadIdx.x;
    const int lane = t & 63;
    const int w  = t >> 6;      // wave id 0..3 -> d base w*64
    const int lg = lane >> 4;   // k-block for A/B fragments; C row group
    const int lr = lane & 15;   // A row (=d) / B col (=a)

    // ---- A fragments (wp bf16; k = lg*8+reg; lg>=2 -> zero) + bias ----
    short8_t afrag[4];
    float4_t acc[4][4];   // [a-strip s][d-tile i]
    const short8_t zero8 = {0, 0, 0, 0, 0, 0, 0, 0};
#pragma unroll
    for (int i = 0; i < 4; ++i) {
        const int d = w * 64 + i * 16 + lr;
        short8_t v = *reinterpret_cast<const short8_t*>(&wp16[d * 16 + (lg & 1) * 8]);
        afrag[i] = (lg < 2) ? v : zero8;
        float4 bv = *reinterpret_cast<const float4*>(&wp_b[w * 64 + i * 16 + lg * 4]);
        float4_t c4 = {bv.x, bv.y, bv.z, bv.w};
#pragma unroll
        for (int s = 0; s < 4; ++s) acc[s][i] = c4;
    }

    // ---- B fragments straight from global (2KB chunk, L2-hot) ----
    const unsigned* sp = samp_dw + (size_t)plane * (AA * 8);
    short8_t bfrag[4];
#pragma unroll
    for (int s = 0; s < 4; ++s) {
        const unsigned* rp = sp + (s * 16 + lr) * 8 + (lg & 1) * 4;
        uint4 u4 = *reinterpret_cast<const uint4*>(rp);
        union { uint4 u; short8_t s8; } uu; uu.u = u4;
        bfrag[s] = uu.s8;
    }

    // ---- 16 MFMAs: acc[s][i] += wp_tile(i) x samp_strip(s) ----
#pragma unroll
    for (int s = 0; s < 4; ++s)
#pragma unroll
        for (int i = 0; i < 4; ++i)
            acc[s][i] = __builtin_amdgcn_mfma_f32_16x16x32_bf16(
                afrag[i], bfrag[s], acc[s][i], 0, 0, 0);

    // ---- stores: plane-contiguous. a = s*16+lr, d = w*64+i*16+lg*4+(0..3) ----
    const size_t ob = (size_t)plane * (AA * DD) + w * 64 + lg * 4;
#pragma unroll
    for (int s = 0; s < 4; ++s) {
        const size_t rb = ob + (size_t)(s * 16 + lr) * DD;
#pragma unroll
        for (int i = 0; i < 4; ++i)
            *reinterpret_cast<float4_t*>(&out[rb + i * 16]) = acc[s][i];
    }
}

// ---------------------------------------------------------------------------
// Fallback (R3 structure) if ws is too small for the samp buffer.
// ---------------------------------------------------------------------------
#define XR_STRIDE 68
#define SA_ST     24

__global__ __launch_bounds__(256) void patch_proj_kernel(
    const float* __restrict__ x,
    const unsigned short* __restrict__ wp16,
    const float* __restrict__ wp_b,
    const float* __restrict__ delta,
    float* __restrict__ out)
{
    const int a = blockIdx.x;
    const int b = blockIdx.y;
    const int t = threadIdx.x;
    const int lane = t & 63;
    const int w  = t >> 6;
    const int lg = lane >> 4;
    const int lr = lane & 15;

    __shared__ float          xr[17 * XR_STRIDE];
    __shared__ unsigned short sampA[64 * SA_ST];

    const float dlt  = delta[b * AA + a];
    const float base = (float)(a * STRIDE_S) - 7.5f + dlt;
    const int   r0   = (int)floorf(base);

    for (int idx = t; idx < 17 * 16; idx += 256) {
        int j  = idx >> 4;
        int nv = idx & 15;
        int row = max(0, min(LL - 1, r0 + j));
        float4 v = *reinterpret_cast<const float4*>(&x[((size_t)b * LL + row) * NN + nv * 4]);
        *reinterpret_cast<float4*>(&xr[j * XR_STRIDE + nv * 4]) = v;
    }

    short8_t afrag[4];
    float4_t acc[4][4];
    const short8_t zero8 = {0, 0, 0, 0, 0, 0, 0, 0};
#pragma unroll
    for (int i = 0; i < 4; ++i) {
        const int d = w * 64 + i * 16 + lr;
        short8_t v = *reinterpret_cast<const short8_t*>(&wp16[d * 16 + (lg & 1) * 8]);
        afrag[i] = (lg < 2) ? v : zero8;
        float4 bv = *reinterpret_cast<const float4*>(&wp_b[w * 64 + i * 16 + lg * 4]);
        float4_t c4 = {bv.x, bv.y, bv.z, bv.w};
#pragma unroll
        for (int s = 0; s < 4; ++s) acc[s][i] = c4;
    }
    __syncthreads();

    {
        const int pp  = t & 7;
        const int nr0 = t >> 3;
        float f_[2]; int j0_[2], j1_[2];
#pragma unroll
        for (int q = 0; q < 2; ++q) {
            int p = pp * 2 + q;
            float xs = base + (float)p;
            xs = fminf(fmaxf(xs, 0.f), (float)(LL - 1));
            int i0 = (int)floorf(xs);
            f_[q]  = xs - (float)i0;
            j0_[q] = i0 - r0;
            j1_[q] = min(i0 + 1, LL - 1) - r0;
        }
#pragma unroll
        for (int h = 0; h < 2; ++h) {
            int n = nr0 + 32 * h;
            unsigned pk = 0;
#pragma unroll
            for (int q = 0; q < 2; ++q) {
                float g0 = xr[j0_[q] * XR_STRIDE + n];
                float g1 = xr[j1_[q] * XR_STRIDE + n];
                float s  = g0 + f_[q] * (g1 - g0);
                pk |= f2bf(s) << (16 * q);
            }
            *reinterpret_cast<unsigned*>(&sampA[n * SA_ST + pp * 2]) = pk;
        }
    }
    __syncthreads();

    short8_t bfrag[4];
#pragma unroll
    for (int s = 0; s < 4; ++s)
        bfrag[s] = *reinterpret_cast<const short8_t*>(
            &sampA[(s * 16 + lr) * SA_ST + (lg & 1) * 8]);

#pragma unroll
    for (int s = 0; s < 4; ++s)
#pragma unroll
        for (int i = 0; i < 4; ++i)
            acc[s][i] = __builtin_amdgcn_mfma_f32_16x16x32_bf16(
                afrag[i], bfrag[s], acc[s][i], 0, 0, 0);

    const size_t ob = (((size_t)b * NN) * AA + a) * DD + w * 64 + lg * 4;
#pragma unroll
    for (int s = 0; s < 4; ++s) {
        const int n = s * 16 + lr;
        const size_t rb = ob + (size_t)n * (AA * DD);
#pragma unroll
        for (int i = 0; i < 4; ++i)
            *reinterpret_cast<float4_t*>(&out[rb + i * 16]) = acc[s][i];
    }
}

// ---------------------------------------------------------------------------
extern "C" void kernel_launch(void* const* d_in, const int* in_sizes, int n_in,
                              void* d_out, int out_size, void* d_ws, size_t ws_size,
                              hipStream_t stream)
{
    const float* x      = (const float*)d_in[0];
    const float* conv_w = (const float*)d_in[1];
    const float* conv_b = (const float*)d_in[2];
    const float* lin_w  = (const float*)d_in[3];
    const float* lin_b  = (const float*)d_in[4];
    const float* wp_w   = (const float*)d_in[5];
    const float* wp_b   = (const float*)d_in[6];
    float* out = (float*)d_out;

    char* wsb = (char*)d_ws;
    float* pool_partial = (float*)wsb;                    // 65536 B
    float* delta        = (float*)(wsb + 65536);          // 16384 B
    unsigned short* wp16 = (unsigned short*)(wsb + 81920);// 8192 B
    unsigned* samp_dw   = (unsigned*)(wsb + 90112);       // 8 MB
    const size_t need = 90112 + (size_t)BB * NN * AA * 8 * 4;

    conv_pool_kernel<<<dim3(8, BB), 256, 0, stream>>>(x, conv_w, conv_b, pool_partial);
    delta_kernel<<<BB, 64, 0, stream>>>(pool_partial, lin_w, lin_b, wp_w, delta, wp16);

    if (ws_size >= need) {
        samp_kernel<<<dim3(AA, BB), 64, 0, stream>>>(x, delta, samp_dw);
        stream_proj_kernel<<<BB * NN, 256, 0, stream>>>(wp16, wp_b, samp_dw, out);
    } else {
        patch_proj_kernel<<<dim3(AA, BB), 256, 0, stream>>>(x, wp16, wp_b, delta, out);
    }
}

// Round 13
// 65.292 us; speedup vs baseline: 1.1239x; 1.1239x over previous
//
#include <hip/hip_runtime.h>
#include <hip/hip_bf16.h>
#include <cmath>

// Problem constants (from reference setup_inputs)
#define BB 64
#define LL 512
#define NN 64
#define AA 64
#define PP 16
#define DD 256
#define MAX_OFF 4.0f
#define STRIDE_S 8

typedef __attribute__((ext_vector_type(8))) short short8_t;   // 8 bf16 = 4 VGPR
typedef __attribute__((ext_vector_type(4))) float float4_t;   // MFMA C/D

// fp32 -> bf16 round-to-nearest-even (finite inputs)
static __device__ __forceinline__ unsigned f2bf(float x) {
    union { float f; unsigned u; } v; v.f = x;
    return (v.u + 0x7FFFu + ((v.u >> 16) & 1u)) >> 16;
}

// ---------------------------------------------------------------------------
// Kernel 1a: conv1d(N->32, k=3, zero pad 1) + ReLU + partial sum over l-chunk.
// grid = (8 chunks, B). block = 256 (o = t&31, lgroup = t>>5, 8 l each).
// ---------------------------------------------------------------------------
__global__ __launch_bounds__(256) void conv_pool_kernel(
    const float* __restrict__ x,        // (B, L, N)
    const float* __restrict__ conv_w,   // (32, N, 3)
    const float* __restrict__ conv_b,   // (32)
    float* __restrict__ pool_partial)   // (B, 8, 32)
{
    const int c = blockIdx.x;   // l-chunk (64 wide)
    const int b = blockIdx.y;
    const int t = threadIdx.x;

    __shared__ float4 wl[3 * 16 * 32];   // [k][nv][o] as float4 over n
    __shared__ float  xl[66 * 64];       // rows c*64-1 .. c*64+64, stride 64
    __shared__ float  red[8][32];

    // stage weights transposed: wl[(k*16+nv)*32 + o] = conv_w[o][nv*4+0..3][k]
    for (int idx = t; idx < 1536; idx += 256) {
        int o  = idx & 31;
        int nv = (idx >> 5) & 15;
        int k  = idx >> 9;
        float4 v;
        v.x = conv_w[(o * 64 + nv * 4 + 0) * 3 + k];
        v.y = conv_w[(o * 64 + nv * 4 + 1) * 3 + k];
        v.z = conv_w[(o * 64 + nv * 4 + 2) * 3 + k];
        v.w = conv_w[(o * 64 + nv * 4 + 3) * 3 + k];
        wl[idx] = v;
    }

    // stage x rows (zero padding outside [0, L))
    const int base_row = c * 64 - 1;
    for (int idx = t; idx < 66 * 16; idx += 256) {
        int j  = idx >> 4;
        int nv = idx & 15;
        int row = base_row + j;
        float4 v = make_float4(0.f, 0.f, 0.f, 0.f);
        if (row >= 0 && row < LL)
            v = *reinterpret_cast<const float4*>(&x[((size_t)b * LL + row) * NN + nv * 4]);
        *reinterpret_cast<float4*>(&xl[j * 64 + nv * 4]) = v;
    }
    __syncthreads();

    const int o  = t & 31;
    const int lg = t >> 5;    // 0..7  -> local l = lg*8 .. lg*8+7

    float s[8];
#pragma unroll
    for (int j = 0; j < 8; ++j) s[j] = 0.f;

#pragma unroll
    for (int nv = 0; nv < 16; ++nv) {
        float4 xv[10];
#pragma unroll
        for (int j = 0; j < 10; ++j)
            xv[j] = *reinterpret_cast<const float4*>(&xl[(lg * 8 + j) * 64 + nv * 4]);
#pragma unroll
        for (int k = 0; k < 3; ++k) {
            float4 w4 = wl[(k * 16 + nv) * 32 + o];
#pragma unroll
            for (int j = 0; j < 8; ++j) {
                s[j] = fmaf(xv[j + k].x, w4.x, s[j]);
                s[j] = fmaf(xv[j + k].y, w4.y, s[j]);
                s[j] = fmaf(xv[j + k].z, w4.z, s[j]);
                s[j] = fmaf(xv[j + k].w, w4.w, s[j]);
            }
        }
    }

    const float cb = conv_b[o];
    float part = 0.f;
#pragma unroll
    for (int j = 0; j < 8; ++j) part += fmaxf(s[j] + cb, 0.f);
    red[lg][o] = part;
    __syncthreads();

    if (t < 32) {
        float sum = 0.f;
#pragma unroll
        for (int g = 0; g < 8; ++g) sum += red[g][t];
        pool_partial[((size_t)b * 8 + c) * 32 + t] = sum;
    }
}

// ---------------------------------------------------------------------------
// Kernel 1b: reduce partials -> pooled mean -> linear(32->A) -> 4*tanh.
// Block 0 additionally converts wp_w to bf16 into ws (read by kernel 2).
// grid = B, block = 64 (one thread per a).
// ---------------------------------------------------------------------------
__global__ __launch_bounds__(64) void delta_kernel(
    const float* __restrict__ pool_partial, // (B, 8, 32)
    const float* __restrict__ lin_w,        // (A, 32)
    const float* __restrict__ lin_b,        // (A)
    const float* __restrict__ wp_w,         // (D, P)
    float* __restrict__ delta,              // (B, A)
    unsigned short* __restrict__ wp16)      // (D*P) bf16
{
    const int b = blockIdx.x;
    const int t = threadIdx.x;
    __shared__ float pooled[32];

    if (t < 32) {
        float s = 0.f;
#pragma unroll
        for (int c = 0; c < 8; ++c) s += pool_partial[((size_t)b * 8 + c) * 32 + t];
        pooled[t] = s * (1.0f / 512.0f);
    }
    __syncthreads();

    float s = lin_b[t];
#pragma unroll
    for (int o = 0; o < 32; ++o) s = fmaf(pooled[o], lin_w[t * 32 + o], s);
    delta[b * AA + t] = MAX_OFF * tanhf(s);

    // one block converts wp_w (4096 floats) to bf16
    if (b == 0) {
        const float4* w4 = reinterpret_cast<const float4*>(wp_w);
        uint2* o2 = reinterpret_cast<uint2*>(wp16);
#pragma unroll
        for (int i = 0; i < 16; ++i) {
            float4 v = w4[i * 64 + t];
            uint2 pk;
            pk.x = f2bf(v.x) | (f2bf(v.y) << 16);
            pk.y = f2bf(v.z) | (f2bf(v.w) << 16);
            o2[i * 64 + t] = pk;
        }
    }
}

// ---------------------------------------------------------------------------
// Kernel 2: bilinear gather + MFMA patch projection (best-measured R3/R5
// structure, 65.5 us total). grid = (A, B) = 4096 blocks, block = 256.
// MFMA: A = wp (M=d), B = samp (N=n), K=16 padded to 32 (A k>=16 zero).
// C layout row=d -> thread's 4 acc regs = 4 consecutive d -> dwordx4.
// ---------------------------------------------------------------------------
#define XR_STRIDE 68   // f32 words; 68%32==4 -> <=2-way bank aliasing (free)
#define SA_ST     24   // bf16 per samp row (16 data + 8 pad); rows 16B-aligned

__global__ __launch_bounds__(256) void patch_proj_kernel(
    const float* __restrict__ x,            // (B, L, N)
    const unsigned short* __restrict__ wp16,// (D, P) bf16
    const float* __restrict__ wp_b,         // (D)
    const float* __restrict__ delta,        // (B, A)
    float* __restrict__ out)                // (B*N, A, D)
{
    const int a = blockIdx.x;
    const int b = blockIdx.y;
    const int t = threadIdx.x;
    const int lane = t & 63;
    const int w  = t >> 6;      // wave id 0..3 -> d base w*64
    const int lg = lane >> 4;   // k-block for A/B fragments; C row group
    const int lr = lane & 15;   // A row (=d) / B col (=n)

    __shared__ float          xr[17 * XR_STRIDE];   // 17 rows of x[b]
    __shared__ unsigned short sampA[64 * SA_ST];    // [n][p] bf16

    const float dlt  = delta[b * AA + a];
    const float base = (float)(a * STRIDE_S) - 7.5f + dlt;   // + p gives xs
    const int   r0   = (int)floorf(base);

    // ---- stage 17 rows of x[b] (clamped rows only read via clamped i0/i1) ----
    for (int idx = t; idx < 17 * 16; idx += 256) {
        int j  = idx >> 4;
        int nv = idx & 15;
        int row = max(0, min(LL - 1, r0 + j));
        float4 v = *reinterpret_cast<const float4*>(&x[((size_t)b * LL + row) * NN + nv * 4]);
        *reinterpret_cast<float4*>(&xr[j * XR_STRIDE + nv * 4]) = v;
    }

    // ---- A fragments (wp, bf16 from global; k = lg*8+reg; lg>=2 -> zero) ----
    short8_t afrag[4];
    float4_t acc[4][4];   // [n-strip s][d-tile i]
    const short8_t zero8 = {0, 0, 0, 0, 0, 0, 0, 0};
#pragma unroll
    for (int i = 0; i < 4; ++i) {
        const int d = w * 64 + i * 16 + lr;
        short8_t v = *reinterpret_cast<const short8_t*>(&wp16[d * 16 + (lg & 1) * 8]);
        afrag[i] = (lg < 2) ? v : zero8;
        // bias for this thread's 4 consecutive d's: d = w*64 + i*16 + lg*4 + j
        float4 bv = *reinterpret_cast<const float4*>(&wp_b[w * 64 + i * 16 + lg * 4]);
        float4_t c4 = {bv.x, bv.y, bv.z, bv.w};
#pragma unroll
        for (int s = 0; s < 4; ++s) acc[s][i] = c4;
    }
    __syncthreads();

    // ---- build samp (fp32 bilinear) -> bf16 pairs into sampA[n][p] ----
    {
        const int pp  = t & 7;    // p-pair index: p = 2*pp, 2*pp+1
        const int nr0 = t >> 3;   // 0..31
        float f_[2]; int j0_[2], j1_[2];
#pragma unroll
        for (int q = 0; q < 2; ++q) {
            int p = pp * 2 + q;
            float xs = base + (float)p;
            xs = fminf(fmaxf(xs, 0.f), (float)(LL - 1));
            int i0 = (int)floorf(xs);
            f_[q]  = xs - (float)i0;
            j0_[q] = i0 - r0;                    // in [0, 16]
            j1_[q] = min(i0 + 1, LL - 1) - r0;   // in [0, 16]
        }
#pragma unroll
        for (int h = 0; h < 2; ++h) {
            int n = nr0 + 32 * h;
            unsigned pk = 0;
#pragma unroll
            for (int q = 0; q < 2; ++q) {
                float g0 = xr[j0_[q] * XR_STRIDE + n];
                float g1 = xr[j1_[q] * XR_STRIDE + n];
                float s  = g0 + f_[q] * (g1 - g0);
                pk |= f2bf(s) << (16 * q);
            }
            *reinterpret_cast<unsigned*>(&sampA[n * SA_ST + pp * 2]) = pk;
        }
    }
    __syncthreads();

    // ---- B fragments (samp): col = lr (n), k = lg*8+reg (lg>=2 x0 = junk ok) ----
    short8_t bfrag[4];
#pragma unroll
    for (int s = 0; s < 4; ++s)
        bfrag[s] = *reinterpret_cast<const short8_t*>(
            &sampA[(s * 16 + lr) * SA_ST + (lg & 1) * 8]);

    // ---- 16 MFMAs: acc[s][i] += wp_tile(i) x samp_strip(s) ----
#pragma unroll
    for (int s = 0; s < 4; ++s)
#pragma unroll
        for (int i = 0; i < 4; ++i)
            acc[s][i] = __builtin_amdgcn_mfma_f32_16x16x32_bf16(
                afrag[i], bfrag[s], acc[s][i], 0, 0, 0);

    // ---- stores: n = s*16+lr, d = w*64 + i*16 + lg*4 + (0..3) -> dwordx4 ----
    const size_t ob = (((size_t)b * NN) * AA + a) * DD + w * 64 + lg * 4;
#pragma unroll
    for (int s = 0; s < 4; ++s) {
        const int n = s * 16 + lr;
        const size_t rb = ob + (size_t)n * (AA * DD);
#pragma unroll
        for (int i = 0; i < 4; ++i)
            *reinterpret_cast<float4_t*>(&out[rb + i * 16]) = acc[s][i];
    }
}

// ---------------------------------------------------------------------------
extern "C" void kernel_launch(void* const* d_in, const int* in_sizes, int n_in,
                              void* d_out, int out_size, void* d_ws, size_t ws_size,
                              hipStream_t stream)
{
    const float* x      = (const float*)d_in[0];
    const float* conv_w = (const float*)d_in[1];
    const float* conv_b = (const float*)d_in[2];
    const float* lin_w  = (const float*)d_in[3];
    const float* lin_b  = (const float*)d_in[4];
    const float* wp_w   = (const float*)d_in[5];
    const float* wp_b   = (const float*)d_in[6];
    float* out = (float*)d_out;

    float* pool_partial = (float*)d_ws;                       // 16384 floats
    float* delta        = pool_partial + 16384;               //  4096 floats
    unsigned short* wp16 = (unsigned short*)(delta + 4096);   //  4096 bf16

    conv_pool_kernel<<<dim3(8, BB), 256, 0, stream>>>(x, conv_w, conv_b, pool_partial);
    delta_kernel<<<BB, 64, 0, stream>>>(pool_partial, lin_w, lin_b, wp_w, delta, wp16);
    patch_proj_kernel<<<dim3(AA, BB), 256, 0, stream>>>(x, wp16, wp_b, delta, out);
}